// Round 4
// baseline (3625.131 us; speedup 1.0000x reference)
//
#include <hip/hip_runtime.h>

// TransportKernel: loss = ||k_ZZ||_F^2 - 2||k_ZY||_F^2 + 0.01 * tr(Z^T (K_XX+1e-3 I)^{-1} Z)
// Cholesky A=LL^T; tr = ||L^{-1}Z||_F^2 (forward solve fused into the factorization).
// All dependencies are stream-ordered (no cross-workgroup flags — XCD L2 non-coherence
// made spin-flag chains stall for tens of µs per hop in round 3).
// Inner step g (64 total): k_trsm2(g)  [subst-TRSM of col g + W diag-solve]
//                          k_pupd(g)   [panel-col updates + W updates + chol(g+1) fused]
// Every 4 steps:           k_upd256(S) [rank-256 trailing SYRK + chol(next head) fused]

#define NN 4096
#define LDA 4100
#define OFF_W   ((size_t)NN*LDA)
#define OFF_ACC (OFF_W + (size_t)NN*4)

__device__ __forceinline__ float rdlane(float v, int l){
    return __int_as_float(__builtin_amdgcn_readlane(__float_as_int(v), l));
}

// ------------------------------------------------------------------
// Single-wave register Cholesky of 64x64 LDS matrix Dm (row-major, stride 68).
// lane = row. Writes L (lower valid; upper garbage, never read) to A at (h,h).
__device__ void wave_chol64(const float* Dm, float* __restrict__ A, int h){
    const int lane = threadIdx.x & 63;
    float row[64];
#pragma unroll
    for (int q=0;q<16;q++){
        float4 v = *(const float4*)(Dm + lane*68 + q*4);
        row[q*4]=v.x; row[q*4+1]=v.y; row[q*4+2]=v.z; row[q*4+3]=v.w;
    }
#pragma unroll
    for (int j=0;j<64;j++){
        float d  = rdlane(row[j], j);
        float sd = sqrtf(d);
        float inv= 1.0f/sd;
        float v  = (lane==j)? sd : row[j]*inv;
        row[j] = v;
#pragma unroll
        for (int c=j+1;c<64;c++){
            float lc = rdlane(v, c);
            row[c] -= v*lc;
        }
    }
#pragma unroll
    for (int q=0;q<16;q++)
        *(float4*)(A + (size_t)(h+lane)*LDA + h + q*4) =
            make_float4(row[q*4],row[q*4+1],row[q*4+2],row[q*4+3]);
}

// ------------------------------------------------------------------
__global__ void k_build_A(const float* __restrict__ X, float* __restrict__ A){
    const int i  = blockIdx.y;
    const int j0 = (blockIdx.x*256 + threadIdx.x)*4;
    const float4 xi = *(const float4*)(X + (size_t)i*4);
    float out[4];
#pragma unroll
    for (int s=0;s<4;s++){
        const float4 xj = *(const float4*)(X + (size_t)(j0+s)*4);
        float d0=xi.x-xj.x, d1=xi.y-xj.y, d2=xi.z-xj.z, d3=xi.w-xj.w;
        float sq = d0*d0+d1*d1+d2*d2+d3*d3;
        float v  = __expf(-0.5f*sq);
        if (i == j0+s) v += 0.001f;
        out[s]=v;
    }
    *(float4*)(A + (size_t)i*LDA + j0) = make_float4(out[0],out[1],out[2],out[3]);
}

// ------------------------------------------------------------------
__global__ void k_init(const float* __restrict__ Z, float* __restrict__ W,
                       double* __restrict__ acc){
    const int i = blockIdx.x*256+threadIdx.x;
    ((float4*)W)[i] = ((const float4*)Z)[i];
    if (blockIdx.x==0 && threadIdx.x==0) acc[0]=0.0;
}

// ------------------------------------------------------------------
__global__ __launch_bounds__(256) void k_chol0(float* __restrict__ A){
    __shared__ float Dm[64*68];
    const int tid = threadIdx.x;
#pragma unroll
    for (int it=0; it<4; ++it){
        int idx = tid + it*256, r = idx>>4, q = idx&15;
        float4 v = *(const float4*)(A + (size_t)r*LDA + q*4);
        *(float4*)&Dm[r*68 + q*4] = v;
    }
    __syncthreads();
    if (tid < 64) wave_chol64(Dm, A, 0);
}

// ------------------------------------------------------------------
// Substitution TRSM of all rows below g vs col g (needs L(g,g)) + W diag-solve(g).
__global__ __launch_bounds__(256) void k_trsm2(float* __restrict__ A, float* __restrict__ W,
                                               int g){
    __shared__ float Ld[64*68];
    __shared__ float dinv[64];
    const int tid = threadIdx.x;
    const int s0  = g*64;
#pragma unroll
    for (int it=0; it<4; ++it){
        int idx = tid + it*256, r = idx>>4, q = idx&15;
        float4 v = *(const float4*)(A + (size_t)(s0+r)*LDA + s0 + q*4);
        *(float4*)&Ld[r*68 + q*4] = v;
    }
    __syncthreads();
    if (tid < 64) dinv[tid] = 1.0f/Ld[tid*68 + tid];
    __syncthreads();

    const int nRB = (66-g)>>2;
    if ((int)blockIdx.x < nRB){
        const int row = s0 + 64 + blockIdx.x*256 + tid;
        const int rl  = row>4095 ? 4095 : row;
        float x[64];
        const float* src = A + (size_t)rl*LDA + s0;
#pragma unroll
        for (int q=0;q<16;q++){
            float4 v = *(const float4*)(src + q*4);
            x[q*4]=v.x; x[q*4+1]=v.y; x[q*4+2]=v.z; x[q*4+3]=v.w;
        }
#pragma unroll
        for (int c=0;c<64;c++){
            float xc = x[c]*dinv[c];
            x[c] = xc;
#pragma unroll
            for (int t=c+1;t<64;t++) x[t] -= xc*Ld[t*68 + c];
        }
        if (row < 4096){
            float* dst = A + (size_t)row*LDA + s0;
#pragma unroll
            for (int q=0;q<16;q++)
                *(float4*)(dst + q*4) = make_float4(x[q*4],x[q*4+1],x[q*4+2],x[q*4+3]);
        }
    } else {
        // W diag solve (wave 0)
        if (tid < 64){
            const int lane = tid;
            float4 wv = *(const float4*)(W + (size_t)(s0+lane)*4);
            float w0=wv.x, w1=wv.y, w2=wv.z, w3=wv.w;
#pragma unroll
            for (int j=0;j<64;j++){
                if (lane==j){ float dj=dinv[j]; w0*=dj; w1*=dj; w2*=dj; w3*=dj; }
                float b0=__shfl(w0,j), b1=__shfl(w1,j), b2=__shfl(w2,j), b3=__shfl(w3,j);
                float l = Ld[lane*68 + j];
                if (lane>j){ w0-=l*b0; w1-=l*b1; w2-=l*b2; w3-=l*b3; }
            }
            *(float4*)(W + (size_t)(s0+lane)*4) = make_float4(w0,w1,w2,w3);
        }
    }
}

// ------------------------------------------------------------------
// Within-panel updates for step g:
//  tile blocks: A(r,c) -= L(r,g) L(c,g)^T for panel cols c in (g, 4S+3], rows r>=c.
//               The (g+1,g+1) block additionally chol-factors its updated tile.
//  W blocks   : W[rows of r] -= L(r,g) * W_g.
__global__ __launch_bounds__(256) void k_pupd(float* __restrict__ A, float* __restrict__ W,
                                              int g){
    __shared__ float Sh[2*4352];
    const int tid = threadIdx.x;
    const int g64 = g*64;
    const int i = g&3, ncols = 3-i;
    int idx = blockIdx.x;
    int c_blk=-1, r_blk=-1;
#pragma unroll
    for (int cc=0; cc<3; ++cc){
        if (cc < ncols && c_blk < 0){
            int cb = g+1+cc, cnt = 64-cb;
            if (idx < cnt){ c_blk=cb; r_blk=cb+idx; }
            else idx -= cnt;
        }
    }
    const int tx = tid&15, ty = tid>>4;

    if (c_blk >= 0){
        float* PrT = Sh;                       // [t][r] for row block
        float* PcT = (r_blk==c_blk) ? Sh : (Sh + 4352);
        const int r0 = r_blk*64, c0 = c_blk*64;
#pragma unroll
        for (int it=0; it<4; ++it){
            int ix = tid + it*256, r = ix>>4, q = ix&15;
            float4 v = *(const float4*)(A + (size_t)(r0+r)*LDA + g64 + q*4);
            PrT[(q*4+0)*68+r]=v.x; PrT[(q*4+1)*68+r]=v.y;
            PrT[(q*4+2)*68+r]=v.z; PrT[(q*4+3)*68+r]=v.w;
        }
        if (r_blk != c_blk){
#pragma unroll
            for (int it=0; it<4; ++it){
                int ix = tid + it*256, r = ix>>4, q = ix&15;
                float4 v = *(const float4*)(A + (size_t)(c0+r)*LDA + g64 + q*4);
                PcT[(q*4+0)*68+r]=v.x; PcT[(q*4+1)*68+r]=v.y;
                PcT[(q*4+2)*68+r]=v.z; PcT[(q*4+3)*68+r]=v.w;
            }
        }
        __syncthreads();
        float acc[4][4]={};
#pragma unroll 8
        for (int t=0;t<64;t++){
            float4 a = *(const float4*)&PrT[t*68 + ty*4];
            float4 b = *(const float4*)&PcT[t*68 + tx*4];
            acc[0][0]+=a.x*b.x; acc[0][1]+=a.x*b.y; acc[0][2]+=a.x*b.z; acc[0][3]+=a.x*b.w;
            acc[1][0]+=a.y*b.x; acc[1][1]+=a.y*b.y; acc[1][2]+=a.y*b.z; acc[1][3]+=a.y*b.w;
            acc[2][0]+=a.z*b.x; acc[2][1]+=a.z*b.y; acc[2][2]+=a.z*b.z; acc[2][3]+=a.z*b.w;
            acc[3][0]+=a.w*b.x; acc[3][1]+=a.w*b.y; acc[3][2]+=a.w*b.z; acc[3][3]+=a.w*b.w;
        }
        if (r_blk==c_blk && c_blk==g+1){
            // next diag: build updated tile in LDS, then chol in-register
            float* Dm = Sh + 4352;
            __syncthreads();
#pragma unroll
            for (int ii=0;ii<4;ii++){
                float4 c = *(const float4*)(A + (size_t)(r0+ty*4+ii)*LDA + c0 + tx*4);
                c.x-=acc[ii][0]; c.y-=acc[ii][1]; c.z-=acc[ii][2]; c.w-=acc[ii][3];
                *(float4*)&Dm[(ty*4+ii)*68 + tx*4] = c;
            }
            __syncthreads();
            if (tid < 64) wave_chol64(Dm, A, r0);
        } else {
#pragma unroll
            for (int ii=0;ii<4;ii++){
                float* p = A + (size_t)(r0+ty*4+ii)*LDA + c0 + tx*4;
                float4 cv = *(float4*)p;
                cv.x-=acc[ii][0]; cv.y-=acc[ii][1]; cv.z-=acc[ii][2]; cv.w-=acc[ii][3];
                *(float4*)p = cv;
            }
        }
    } else {
        // ---------- W panel update ----------
        const int wr0 = (g+1+idx)*64;
        float* Lt = Sh;          // [64][68] row-major
        float* Ws = Sh + 4352;   // [64][4]
#pragma unroll
        for (int it=0; it<4; ++it){
            int ix = tid + it*256, r = ix>>4, q = ix&15;
            float4 v = *(const float4*)(A + (size_t)(wr0+r)*LDA + g64 + q*4);
            *(float4*)&Lt[r*68 + q*4] = v;
        }
        if (tid < 64) *(float4*)&Ws[tid*4] = *(const float4*)(W + (size_t)(g64+tid)*4);
        __syncthreads();
        const int row = tid>>2, cw = tid&3;
        float s = 0.f;
#pragma unroll 16
        for (int t=0;t<64;t++) s += Lt[row*68+t]*Ws[t*4+cw];
        float* wp = W + (size_t)(wr0+row)*4 + cw;
        *wp = *wp - s;
    }
}

// ------------------------------------------------------------------
// Rank-256 trailing update (128x128 tiles) + fused chol of next panel head.
__global__ __launch_bounds__(256) void k_upd256(float* __restrict__ A, int S){
    __shared__ float S_[8704];
    const int tid = threadIdx.x;
    const int k0 = S*256, base = k0+256;
    const int T2 = (4096-base)>>7;
    const int nT2 = T2*(T2+1)/2;
    const int tx = tid&15, ty = tid>>4;

    if ((int)blockIdx.x == nT2){
        // chol block: rank-256 update of A(base,base) 64x64, then chol
        float* PT = S_;           // [t][r], stride 68
        float* Dm = S_ + 4352;
        float acc[4][4]={};
        for (int kk=0; kk<4; ++kk){
            __syncthreads();
#pragma unroll
            for (int it=0; it<4; ++it){
                int ix = tid + it*256, r = ix>>4, q = ix&15;
                float4 v = *(const float4*)(A + (size_t)(base+r)*LDA + k0 + kk*64 + q*4);
                PT[(q*4+0)*68+r]=v.x; PT[(q*4+1)*68+r]=v.y;
                PT[(q*4+2)*68+r]=v.z; PT[(q*4+3)*68+r]=v.w;
            }
            __syncthreads();
#pragma unroll 8
            for (int t=0;t<64;t++){
                float4 a = *(const float4*)&PT[t*68 + ty*4];
                float4 b = *(const float4*)&PT[t*68 + tx*4];
                acc[0][0]+=a.x*b.x; acc[0][1]+=a.x*b.y; acc[0][2]+=a.x*b.z; acc[0][3]+=a.x*b.w;
                acc[1][0]+=a.y*b.x; acc[1][1]+=a.y*b.y; acc[1][2]+=a.y*b.z; acc[1][3]+=a.y*b.w;
                acc[2][0]+=a.z*b.x; acc[2][1]+=a.z*b.y; acc[2][2]+=a.z*b.z; acc[2][3]+=a.z*b.w;
                acc[3][0]+=a.w*b.x; acc[3][1]+=a.w*b.y; acc[3][2]+=a.w*b.z; acc[3][3]+=a.w*b.w;
            }
        }
        __syncthreads();
#pragma unroll
        for (int ii=0;ii<4;ii++){
            float4 c = *(const float4*)(A + (size_t)(base+ty*4+ii)*LDA + base + tx*4);
            c.x-=acc[ii][0]; c.y-=acc[ii][1]; c.z-=acc[ii][2]; c.w-=acc[ii][3];
            *(float4*)&Dm[(ty*4+ii)*68 + tx*4] = c;
        }
        __syncthreads();
        if (tid < 64) wave_chol64(Dm, A, base);
        return;
    }

    float* Sa = S_;
    float* Sb = S_ + 4224;
    int t2 = blockIdx.x;
    int bi = (int)((sqrtf(8.f*(float)t2+1.f)-1.f)*0.5f);
    while ((bi+1)*(bi+2)/2 <= t2) ++bi;
    while (bi*(bi+1)/2 > t2) --bi;
    const int bj = t2 - bi*(bi+1)/2;
    const int r0 = base + bi*128, c0 = base + bj*128;
    const bool dg = (bi==bj);
    const float* Sbp = dg ? Sa : Sb;
    int row_[4], q_[4];
#pragma unroll
    for (int it=0;it<4;++it){ int ix=tid+it*256; row_[it]=ix>>3; q_[it]=ix&7; }
    float4 ra[4], rb[4];
#pragma unroll
    for (int it=0;it<4;++it){
        ra[it] = *(const float4*)(A + (size_t)(r0+row_[it])*LDA + k0 + q_[it]*4);
        if (!dg) rb[it] = *(const float4*)(A + (size_t)(c0+row_[it])*LDA + k0 + q_[it]*4);
    }
    float acc[8][8]={};
    for (int kk=0;kk<8;++kk){
        __syncthreads();
#pragma unroll
        for (int it=0;it<4;++it){
            Sa[(q_[it]*4+0)*132+row_[it]]=ra[it].x; Sa[(q_[it]*4+1)*132+row_[it]]=ra[it].y;
            Sa[(q_[it]*4+2)*132+row_[it]]=ra[it].z; Sa[(q_[it]*4+3)*132+row_[it]]=ra[it].w;
            if (!dg){
                Sb[(q_[it]*4+0)*132+row_[it]]=rb[it].x; Sb[(q_[it]*4+1)*132+row_[it]]=rb[it].y;
                Sb[(q_[it]*4+2)*132+row_[it]]=rb[it].z; Sb[(q_[it]*4+3)*132+row_[it]]=rb[it].w;
            }
        }
        __syncthreads();
        if (kk < 7){
            const int kb = k0 + (kk+1)*32;
#pragma unroll
            for (int it=0;it<4;++it){
                ra[it] = *(const float4*)(A + (size_t)(r0+row_[it])*LDA + kb + q_[it]*4);
                if (!dg) rb[it] = *(const float4*)(A + (size_t)(c0+row_[it])*LDA + kb + q_[it]*4);
            }
        }
#pragma unroll 4
        for (int t=0;t<32;++t){
            float4 a0 = *(const float4*)&Sa[t*132 + ty*8];
            float4 a1 = *(const float4*)&Sa[t*132 + ty*8 + 4];
            float4 b0 = *(const float4*)&Sbp[t*132 + tx*8];
            float4 b1 = *(const float4*)&Sbp[t*132 + tx*8 + 4];
            float av[8]={a0.x,a0.y,a0.z,a0.w,a1.x,a1.y,a1.z,a1.w};
            float bv[8]={b0.x,b0.y,b0.z,b0.w,b1.x,b1.y,b1.z,b1.w};
#pragma unroll
            for (int ii=0;ii<8;ii++)
#pragma unroll
                for (int jj=0;jj<8;jj++) acc[ii][jj] += av[ii]*bv[jj];
        }
    }
    // subtract-store; the first 64x64 quarter of tile (0,0) is owned by the chol block
#pragma unroll
    for (int ii=0;ii<8;ii++){
        const int r = r0 + ty*8 + ii;
        const int c = c0 + tx*8;
        if (r < base+64 && c < base+64) continue;
        float* p = A + (size_t)r*LDA + c;
        float4 c1 = *(float4*)p;
        c1.x-=acc[ii][0]; c1.y-=acc[ii][1]; c1.z-=acc[ii][2]; c1.w-=acc[ii][3];
        *(float4*)p = c1;
        float4 c2 = *(float4*)(p+4);
        c2.x-=acc[ii][4]; c2.y-=acc[ii][5]; c2.z-=acc[ii][6]; c2.w-=acc[ii][7];
        *(float4*)(p+4) = c2;
    }
}

// ------------------------------------------------------------------
__global__ void k_lossfit(const float* __restrict__ Z, const float* __restrict__ Y,
                          double* __restrict__ acc){
    const int tid=threadIdx.x;
    const int i0=blockIdx.x*8;
    double s=0.0;
    for (int ii=0;ii<8;ii++){
        const float4 zi = *(const float4*)(Z + (size_t)(i0+ii)*4);
        for (int j=tid;j<NN;j+=256){
            float4 zj = *(const float4*)(Z + (size_t)j*4);
            float4 yj = *(const float4*)(Y + (size_t)j*4);
            float d0=zi.x-zj.x, d1=zi.y-zj.y, d2=zi.z-zj.z, d3=zi.w-zj.w;
            float dzz = d0*d0+d1*d1+d2*d2+d3*d3;
            d0=zi.x-yj.x; d1=zi.y-yj.y; d2=zi.z-yj.z; d3=zi.w-yj.w;
            float dzy = d0*d0+d1*d1+d2*d2+d3*d3;
            s += (double)(__expf(-dzz) - 2.f*__expf(-dzy));
        }
    }
    for (int o=32;o;o>>=1) s += __shfl_down(s,o);
    __shared__ double ps[4];
    if ((tid&63)==0) ps[tid>>6]=s;
    __syncthreads();
    if (tid==0) atomicAdd(acc, ps[0]+ps[1]+ps[2]+ps[3]);
}

__global__ void k_finish(const float* __restrict__ W, const double* __restrict__ acc,
                         float* __restrict__ out){
    const int tid=threadIdx.x;
    double s=0.0;
    for (int r=tid;r<NN;r+=256){
        float4 v=*(const float4*)(W+(size_t)r*4);
        s += (double)v.x*v.x+(double)v.y*v.y+(double)v.z*v.z+(double)v.w*v.w;
    }
    for (int o=32;o;o>>=1) s += __shfl_down(s,o);
    __shared__ double ps[4];
    if ((tid&63)==0) ps[tid>>6]=s;
    __syncthreads();
    if (tid==0) out[0] = (float)(acc[0] + 0.01*(ps[0]+ps[1]+ps[2]+ps[3]));
}

// ------------------------------------------------------------------
extern "C" void kernel_launch(void* const* d_in, const int* in_sizes, int n_in,
                              void* d_out, int out_size, void* d_ws, size_t ws_size,
                              hipStream_t stream){
    const float* X=(const float*)d_in[0];
    const float* Y=(const float*)d_in[1];
    const float* Z=(const float*)d_in[2];
    float* ws   = (float*)d_ws;
    float* A    = ws;
    float* W    = ws + OFF_W;
    double* acc = (double*)(ws + OFF_ACC);

    if (ws_size < (OFF_ACC)*sizeof(float) + 16) return;  // loud failure

    k_init   <<<16,256,0,stream>>>(Z, W, acc);
    k_build_A<<<dim3(NN/1024,NN),256,0,stream>>>(X, A);
    k_lossfit<<<512,256,0,stream>>>(Z, Y, acc);
    k_chol0  <<<1,256,0,stream>>>(A);

    for (int g=0; g<64; ++g){
        const int nRB = (66-g)>>2;
        k_trsm2<<<nRB+1,256,0,stream>>>(A, W, g);
        const int i = g&3, ncols = 3-i;
        int ntile = 0;
        for (int cc=0; cc<ncols; ++cc) ntile += 64-(g+1+cc);
        const int nW = 63-g;
        if (ntile+nW > 0) k_pupd<<<ntile+nW,256,0,stream>>>(A, W, g);
        if (i==3 && g<63){
            const int S = g>>2;
            const int T2 = (4096-(S+1)*256)>>7;
            const int nT2 = T2*(T2+1)/2;
            k_upd256<<<nT2+1,256,0,stream>>>(A, S);
        }
    }
    k_finish<<<1,256,0,stream>>>(W, acc, (float*)d_out);
}